// Round 2
// baseline (132.394 us; speedup 1.0000x reference)
//
#include <hip/hip_runtime.h>
#include <cstddef>

namespace {

constexpr int kB = 32, kT = 512, kD = 64, kP = 16, kNW = 63, kDM = 512;
constexpr int kRows = kD * kNW + kT;     // 4544 output rows per batch
constexpr int kTT = 16;                  // t-rows per feature block
constexpr int kNBT = kB * kD;            // 2048 temporal blocks
constexpr int kNBF = kB * (kT / kTT);    // 1024 feature blocks

// Force a scalar (s_load) read of a block-uniform x element: readfirstlane
// pins the index into an SGPR, so the address is provably uniform and the
// load goes through the scalar K$ pipe instead of LDS/VMEM broadcast.
__device__ __forceinline__ float uload(const float* __restrict__ p, int idx) {
    return p[__builtin_amdgcn_readfirstlane(idx)];
}

__global__ __launch_bounds__(512)
void patch_embed(const float* __restrict__ x,
                 const float* __restrict__ Wt,
                 const float* __restrict__ bt,
                 const float* __restrict__ Wd,
                 const float* __restrict__ bd,
                 float* __restrict__ out)
{
    const int m = threadIdx.x;       // output channel, 0..511
    int blk = blockIdx.x;

    if (blk < kNBT) {
        // ---------------- temporal: out[b, d*63+w, m] = sum_p x[b,8w+p,d]*Wt[m,p] + bt[m]
        const int b = blk >> 6;          // / kD
        const int d = blk & (kD - 1);
        const int xbase = (b * kT) * kD + d;   // < 2^21, int-safe

        const float4* wtp = (const float4*)(Wt + m * kP);
        const float4 q0 = wtp[0], q1 = wtp[1], q2 = wtp[2], q3 = wtp[3];
        const float bias = bt[m];

        size_t obase = (size_t)b * kRows * kDM + (size_t)(d * kNW) * kDM + m;

        // sliding 16-float window of the x column, held in SGPRs
        float win[kP];
        #pragma unroll
        for (int p = 0; p < kP; ++p)
            win[p] = uload(x, xbase + p * kD);

        #pragma unroll
        for (int w = 0; w < kNW; ++w) {
            float a0 = win[0]  * q0.x + win[1]  * q0.y;
            float a1 = win[2]  * q0.z + win[3]  * q0.w;
            float a2 = win[4]  * q1.x + win[5]  * q1.y;
            float a3 = win[6]  * q1.z + win[7]  * q1.w;
            a0 += win[8]  * q2.x + win[9]  * q2.y;
            a1 += win[10] * q2.z + win[11] * q2.w;
            a2 += win[12] * q3.x + win[13] * q3.y;
            a3 += win[14] * q3.z + win[15] * q3.w;
            float acc = bias + ((a0 + a1) + (a2 + a3));
            __builtin_nontemporal_store(acc, out + obase + (size_t)w * kDM);
            if (w < kNW - 1) {
                #pragma unroll
                for (int p = 0; p < 8; ++p) win[p] = win[p + 8];
                #pragma unroll
                for (int p = 0; p < 8; ++p)
                    win[8 + p] = uload(x, xbase + (w * 8 + 16 + p) * kD);
            }
        }
    } else {
        // ---------------- feature: out[b, 4032+t, m] = sum_d x[b,t,d]*Wd[m,d] + bd[m]
        blk -= kNBT;
        const int b  = blk >> 5;                 // / (kT/kTT)
        const int t0 = (blk & 31) * kTT;
        const int xrow0 = (b * kT + t0) * kD;

        // Wd row in registers: 64 floats/thread, amortized over 16 output rows
        float wr[kD];
        const float4* wdp = (const float4*)(Wd + (size_t)m * kD);
        #pragma unroll
        for (int i = 0; i < kD / 4; ++i) {
            float4 v = wdp[i];
            wr[4*i+0] = v.x; wr[4*i+1] = v.y; wr[4*i+2] = v.z; wr[4*i+3] = v.w;
        }
        const float bias = bd[m];

        size_t obase = (size_t)b * kRows * kDM + (size_t)(kD * kNW + t0) * kDM + m;
        for (int tt = 0; tt < kTT; ++tt) {
            const int rbase = xrow0 + tt * kD;
            float a0 = 0.f, a1 = 0.f, a2 = 0.f, a3 = 0.f;
            #pragma unroll
            for (int i = 0; i < kD; i += 4) {
                // x row is wave-uniform -> SGPRs via s_load (merged to dwordx16)
                float s0 = uload(x, rbase + i + 0);
                float s1 = uload(x, rbase + i + 1);
                float s2 = uload(x, rbase + i + 2);
                float s3 = uload(x, rbase + i + 3);
                a0 += s0 * wr[i + 0];
                a1 += s1 * wr[i + 1];
                a2 += s2 * wr[i + 2];
                a3 += s3 * wr[i + 3];
            }
            float acc = bias + ((a0 + a1) + (a2 + a3));
            __builtin_nontemporal_store(acc, out + obase + (size_t)tt * kDM);
        }
    }
}

} // namespace

extern "C" void kernel_launch(void* const* d_in, const int* in_sizes, int n_in,
                              void* d_out, int out_size, void* d_ws, size_t ws_size,
                              hipStream_t stream) {
    const float* x  = (const float*)d_in[0];
    const float* Wt = (const float*)d_in[1];
    const float* bt = (const float*)d_in[2];
    const float* Wd = (const float*)d_in[3];
    const float* bd = (const float*)d_in[4];
    float* out = (float*)d_out;

    dim3 grid(kNBT + kNBF);
    dim3 block(512);
    hipLaunchKernelGGL(patch_embed, grid, block, 0, stream, x, Wt, bt, Wd, bd, out);
}

// Round 3
// 102.064 us; speedup vs baseline: 1.2972x; 1.2972x over previous
//
#include <hip/hip_runtime.h>
#include <cstddef>

namespace {

constexpr int kB = 32, kT = 512, kD = 64, kP = 16, kNW = 63, kDM = 512;
constexpr int kRows = kD * kNW + kT;     // 4544 output rows per batch
constexpr int kTT = 16;                  // t-rows per feature block
constexpr int kNBT = kB * kD;            // 2048 temporal blocks
constexpr int kNBF = kB * (kT / kTT);    // 1024 feature blocks

// Broadcast lane `lane`'s value of v to all lanes (lands in an SGPR).
// Pure VALU op — no LDS pipe, no memory latency, no waitcnt.
__device__ __forceinline__ float rl(float v, int lane) {
    return __int_as_float(__builtin_amdgcn_readlane(__float_as_int(v), lane));
}

__global__ __launch_bounds__(512)
void patch_embed(const float* __restrict__ x,
                 const float* __restrict__ Wt,
                 const float* __restrict__ bt,
                 const float* __restrict__ Wd,
                 const float* __restrict__ bd,
                 float* __restrict__ out)
{
    const int m    = threadIdx.x;    // output channel, 0..511
    const int lane = m & 63;
    int blk = blockIdx.x;

    if (blk < kNBT) {
        // ---- temporal: out[b, d*63+w, m] = sum_p x[b,8w+p,d]*Wt[m,p] + bt[m]
        __shared__ float xs[kT];     // one x column, staged once
        const int b = blk >> 6;
        const int d = blk & (kD - 1);

        xs[m] = x[(b * kT + m) * kD + d];

        const float4* wtp = (const float4*)(Wt + m * kP);
        const float4 q0 = wtp[0], q1 = wtp[1], q2 = wtp[2], q3 = wtp[3];
        const float bias = bt[m];
        __syncthreads();

        // lane l holds column elements 8l..8l+7 in registers (only LDS reads left)
        float4 xa = ((const float4*)xs)[lane * 2];
        float4 xb = ((const float4*)xs)[lane * 2 + 1];
        float xc[8] = {xa.x, xa.y, xa.z, xa.w, xb.x, xb.y, xb.z, xb.w};

        // 16-float sliding window, wave-uniform (SGPRs)
        float win[kP];
        #pragma unroll
        for (int j = 0; j < 8; ++j) {
            win[j]     = rl(xc[j], 0);
            win[8 + j] = rl(xc[j], 1);
        }

        size_t obase = (size_t)b * kRows * kDM + (size_t)(d * kNW) * kDM + m;
        for (int w = 0; w < kNW; ++w) {
            float a0 = win[0]  * q0.x + win[1]  * q0.y;
            float a1 = win[2]  * q0.z + win[3]  * q0.w;
            float a2 = win[4]  * q1.x + win[5]  * q1.y;
            float a3 = win[6]  * q1.z + win[7]  * q1.w;
            a0 += win[8]  * q2.x + win[9]  * q2.y;
            a1 += win[10] * q2.z + win[11] * q2.w;
            a2 += win[12] * q3.x + win[13] * q3.y;
            a3 += win[14] * q3.z + win[15] * q3.w;
            float acc = bias + ((a0 + a1) + (a2 + a3));
            __builtin_nontemporal_store(acc, out + obase + (size_t)w * kDM);
            if (w < kNW - 1) {
                #pragma unroll
                for (int j = 0; j < 8; ++j) win[j] = win[j + 8];
                #pragma unroll
                for (int j = 0; j < 8; ++j) win[8 + j] = rl(xc[j], w + 2);
            }
        }
    } else {
        // ---- feature: out[b, 4032+t, m] = sum_d x[b,t,d]*Wd[m,d] + bd[m]
        blk -= kNBT;
        const int b  = blk >> 5;                 // / (kT/kTT)
        const int t0 = (blk & 31) * kTT;

        // lane l holds x-chunk flat elements [16l, 16l+16) — coalesced float4s
        const float4* xbase = (const float4*)(x + (size_t)(b * kT + t0) * kD);
        float xr[16];
        #pragma unroll
        for (int i = 0; i < 4; ++i) {
            float4 v = xbase[lane * 4 + i];
            xr[4*i+0] = v.x; xr[4*i+1] = v.y; xr[4*i+2] = v.z; xr[4*i+3] = v.w;
        }

        // Wd row in registers, amortized over 16 output rows
        float wr[kD];
        const float4* wdp = (const float4*)(Wd + (size_t)m * kD);
        #pragma unroll
        for (int i = 0; i < kD / 4; ++i) {
            float4 v = wdp[i];
            wr[4*i+0] = v.x; wr[4*i+1] = v.y; wr[4*i+2] = v.z; wr[4*i+3] = v.w;
        }
        const float bias = bd[m];

        size_t obase = (size_t)b * kRows * kDM + (size_t)(kD * kNW + t0) * kDM + m;
        for (int tt = 0; tt < kTT; ++tt) {
            // row tt lives in lanes 4tt..4tt+3, regs 0..15 each
            const int l0 = tt * 4;
            float a0 = 0.f, a1 = 0.f, a2 = 0.f, a3 = 0.f;
            #pragma unroll
            for (int r = 0; r < 4; ++r) {
                #pragma unroll
                for (int j = 0; j < 16; j += 4) {
                    a0 += rl(xr[j + 0], l0 + r) * wr[r * 16 + j + 0];
                    a1 += rl(xr[j + 1], l0 + r) * wr[r * 16 + j + 1];
                    a2 += rl(xr[j + 2], l0 + r) * wr[r * 16 + j + 2];
                    a3 += rl(xr[j + 3], l0 + r) * wr[r * 16 + j + 3];
                }
            }
            float acc = bias + ((a0 + a1) + (a2 + a3));
            __builtin_nontemporal_store(acc, out + obase + (size_t)tt * kDM);
        }
    }
}

} // namespace

extern "C" void kernel_launch(void* const* d_in, const int* in_sizes, int n_in,
                              void* d_out, int out_size, void* d_ws, size_t ws_size,
                              hipStream_t stream) {
    const float* x  = (const float*)d_in[0];
    const float* Wt = (const float*)d_in[1];
    const float* bt = (const float*)d_in[2];
    const float* Wd = (const float*)d_in[3];
    const float* bd = (const float*)d_in[4];
    float* out = (float*)d_out;

    dim3 grid(kNBT + kNBF);
    dim3 block(512);
    hipLaunchKernelGGL(patch_embed, grid, block, 0, stream, x, Wt, bt, Wd, bd, out);
}